// Round 1
// 465.226 us; speedup vs baseline: 1.0354x; 1.0354x over previous
//
#include <hip/hip_runtime.h>
#include <math.h>

#define N_ENTITY 64368
#define N_REL 12
#define DIM 128
#define NB 8
#define N_ITEM 6924
#define NEDGE 1000000
#define BATCH 128
#define SEQL 32
#define ITEM_TILE 32
#define CAP 96   // fixed bucket capacity per dst; P(Poisson(15.5) >= 96) < 1e-40

// ---------------------------------------------------------------------------
// Phase 1: single-pass bucketing.  Fixed-stride CAP-slot buckets per dst with
// atomic cursors (replaces count+scan+fill).  int4-vectorized edge reads.
// cursor[d] ends holding the TRUE degree (uncapped); stores are clamped.
// ---------------------------------------------------------------------------
__global__ __launch_bounds__(256) void fill_kernel(
    const int* __restrict__ e_src, const int* __restrict__ e_dst,
    const int* __restrict__ e_type, int* __restrict__ cursor,
    int* __restrict__ bucket)
{
    int gid = blockIdx.x * 256 + threadIdx.x;
    if (gid * 4 >= NEDGE) return;
    int4 s4 = reinterpret_cast<const int4*>(e_src)[gid];
    int4 d4 = reinterpret_cast<const int4*>(e_dst)[gid];
    int4 t4 = reinterpret_cast<const int4*>(e_type)[gid];

    #pragma unroll
    for (int k = 0; k < 4; ++k) {
        int s = (k == 0) ? s4.x : (k == 1) ? s4.y : (k == 2) ? s4.z : s4.w;
        int d = (k == 0) ? d4.x : (k == 1) ? d4.y : (k == 2) ? d4.z : d4.w;
        int t = (k == 0) ? t4.x : (k == 1) ? t4.y : (k == 2) ? t4.z : t4.w;
        if (d < N_ITEM) {
            int pos = atomicAdd(&cursor[d], 1);
            if (pos < CAP) bucket[d * CAP + pos] = s | (t << 17);
        }
    }
}

// ---------------------------------------------------------------------------
// Phase 2: one wave per item row, split into two 32-lane halves that each
// process a DIFFERENT edge per iteration (2x memory-level parallelism) with
// float4 gathers (16B/lane).  Each half covers all 128 dims (32 lanes x 4).
// Halves are summed with shfl_xor(32) before the fused epilogue
// (mean-normalize by TRUE degree + root + bias).
// ---------------------------------------------------------------------------
__global__ __launch_bounds__(256) void aggregate_kernel(
    const int* __restrict__ cursor, const int* __restrict__ bucket,
    const float* __restrict__ basis, const float* __restrict__ att,
    const float* __restrict__ root, const float* __restrict__ bias,
    float* __restrict__ nodes)
{
    __shared__ float att_s[N_REL * NB];
    if (threadIdx.x < N_REL * NB) att_s[threadIdx.x] = att[threadIdx.x];
    __syncthreads();

    int wave = threadIdx.x >> 6;
    int lane = threadIdx.x & 63;
    int half = lane >> 5;      // 0 or 1: which edge of the pair
    int l32  = lane & 31;      // covers dims 4*l32 .. 4*l32+3
    int row  = blockIdx.x * 4 + wave;
    if (row >= N_ITEM) return;

    int deg = cursor[row];               // true degree
    int n   = (deg > CAP) ? CAP : deg;   // edges actually stored

    float4 acc = make_float4(0.f, 0.f, 0.f, 0.f);
    const int* bkt = bucket + (size_t)row * CAP;

    for (int base = 0; base < n; base += 64) {
        int m = n - base; if (m > 64) m = 64;
        int pk = 0;
        if (lane < m) pk = bkt[base + lane];
        for (int j = 0; j < m; j += 2) {
            int e     = j + half;
            int esafe = (e < m) ? e : 0;
            int p     = __shfl(pk, esafe);      // all lanes active in shfl
            if (e < m) {
                int ss = p & 0x1FFFF;
                int tt = p >> 17;
                const float* bp = basis + (size_t)ss * DIM + (l32 << 2);
                #pragma unroll
                for (int b = 0; b < NB; ++b) {
                    float  a = att_s[tt * NB + b];
                    float4 v = *reinterpret_cast<const float4*>(
                                   bp + (size_t)b * (N_ENTITY * DIM));
                    acc.x += a * v.x;
                    acc.y += a * v.y;
                    acc.z += a * v.z;
                    acc.w += a * v.w;
                }
            }
        }
    }

    // combine the two half-wave partial sums (same dims, different edges)
    acc.x += __shfl_xor(acc.x, 32);
    acc.y += __shfl_xor(acc.y, 32);
    acc.z += __shfl_xor(acc.z, 32);
    acc.w += __shfl_xor(acc.w, 32);

    if (half == 0) {
        float  inv = 1.0f / fmaxf((float)deg, 1.0f);
        float4 r   = *reinterpret_cast<const float4*>(root + (size_t)row * DIM + (l32 << 2));
        float4 bs  = *reinterpret_cast<const float4*>(bias + (l32 << 2));
        float4 o;
        o.x = acc.x * inv + r.x + bs.x;
        o.y = acc.y * inv + r.y + bs.y;
        o.z = acc.z * inv + r.z + bs.z;
        o.w = acc.w * inv + r.w + bs.w;
        *reinterpret_cast<float4*>(nodes + (size_t)row * DIM + (l32 << 2)) = o;
    }
}

// ---------------------------------------------------------------------------
// Phase 3: attention pool.  One block per batch row.  (unchanged)
// ---------------------------------------------------------------------------
__global__ __launch_bounds__(256) void pool_kernel(
    const float* __restrict__ nodes, const int* __restrict__ seed_ids,
    const int* __restrict__ seed_len, const float* __restrict__ attn_a,
    const float* __restrict__ attn_b, float* __restrict__ u)
{
    __shared__ float h[SEQL * 132];
    __shared__ float ev[SEQL];
    __shared__ float attw[SEQL];
    __shared__ int   seeds[SEQL];

    int b   = blockIdx.x;
    int tid = threadIdx.x;
    int len = seed_len[b];

    if (tid < SEQL) seeds[tid] = seed_ids[b * SEQL + tid];
    __syncthreads();

    for (int idx = tid; idx < SEQL * (DIM / 4); idx += 256) {
        int l  = idx >> 5;
        int kq = idx & 31;
        float4 v = reinterpret_cast<const float4*>(nodes)[(size_t)seeds[l] * 32 + kq];
        *reinterpret_cast<float4*>(h + l * 132 + kq * 4) = v;
    }
    __syncthreads();

    {
        int l = tid >> 3;
        int j = tid & 7;
        float dot[16];
        #pragma unroll
        for (int i = 0; i < 16; ++i) dot[i] = 0.f;
        const float* hr = h + l * 132;
        for (int k = 0; k < DIM; ++k) {
            float hv = hr[k];
            const float4* ar = reinterpret_cast<const float4*>(attn_a + k * DIM + j * 16);
            float4 a0 = ar[0], a1 = ar[1], a2 = ar[2], a3 = ar[3];
            dot[0]  += hv * a0.x; dot[1]  += hv * a0.y; dot[2]  += hv * a0.z; dot[3]  += hv * a0.w;
            dot[4]  += hv * a1.x; dot[5]  += hv * a1.y; dot[6]  += hv * a1.z; dot[7]  += hv * a1.w;
            dot[8]  += hv * a2.x; dot[9]  += hv * a2.y; dot[10] += hv * a2.z; dot[11] += hv * a2.w;
            dot[12] += hv * a3.x; dot[13] += hv * a3.y; dot[14] += hv * a3.z; dot[15] += hv * a3.w;
        }
        float sum = 0.f;
        #pragma unroll
        for (int i = 0; i < 16; ++i) sum += tanhf(dot[i]) * attn_b[j * 16 + i];
        sum += __shfl_xor(sum, 1);
        sum += __shfl_xor(sum, 2);
        sum += __shfl_xor(sum, 4);
        if (j == 0) ev[l] = sum;
    }
    __syncthreads();

    if (tid < SEQL) {
        float val = (tid < len) ? ev[tid] : -3.0e38f;
        float m = val;
        #pragma unroll
        for (int off = 16; off > 0; off >>= 1) m = fmaxf(m, __shfl_xor(m, off));
        float p = (tid < len) ? expf(val - m) : 0.f;
        float ssum = p;
        #pragma unroll
        for (int off = 16; off > 0; off >>= 1) ssum += __shfl_xor(ssum, off);
        attw[tid] = (len > 0) ? p / ssum : 0.f;
    }
    __syncthreads();

    if (tid < DIM) {
        float acc = 0.f;
        #pragma unroll
        for (int l = 0; l < SEQL; ++l) acc += attw[l] * h[l * 132 + tid];
        u[(size_t)b * DIM + tid] = acc;
    }
}

// ---------------------------------------------------------------------------
// Phase 4: scores[b,i] = u[b,:] . nodes[i,:] + out_bias[i]  (unchanged)
// ---------------------------------------------------------------------------
__global__ __launch_bounds__(256) void score_kernel(
    const float* __restrict__ nodes, const float* __restrict__ u,
    const float* __restrict__ out_bias, float* __restrict__ out)
{
    __shared__ float us[BATCH * DIM];
    __shared__ float ns[ITEM_TILE * 132];
    int tid   = threadIdx.x;
    int item0 = blockIdx.x * ITEM_TILE;

    for (int idx = tid; idx < BATCH * (DIM / 4); idx += 256)
        reinterpret_cast<float4*>(us)[idx] = reinterpret_cast<const float4*>(u)[idx];

    for (int idx = tid; idx < ITEM_TILE * (DIM / 4); idx += 256) {
        int j  = idx >> 5;
        int kq = idx & 31;
        int item = item0 + j;
        float4 v = make_float4(0.f, 0.f, 0.f, 0.f);
        if (item < N_ITEM) v = reinterpret_cast<const float4*>(nodes)[(size_t)item * 32 + kq];
        *reinterpret_cast<float4*>(ns + j * 132 + kq * 4) = v;
    }
    __syncthreads();

    int jg = tid & 15;
    int bg = tid >> 4;
    float acc0[8], acc1[8];
    #pragma unroll
    for (int i = 0; i < 8; ++i) { acc0[i] = 0.f; acc1[i] = 0.f; }
    const float* n0p = ns + (jg * 2 + 0) * 132;
    const float* n1p = ns + (jg * 2 + 1) * 132;
    for (int k = 0; k < DIM; k += 4) {
        float4 n0 = *reinterpret_cast<const float4*>(n0p + k);
        float4 n1 = *reinterpret_cast<const float4*>(n1p + k);
        #pragma unroll
        for (int bb = 0; bb < 8; ++bb) {
            float4 uv = *reinterpret_cast<const float4*>(us + (bg * 8 + bb) * DIM + k);
            acc0[bb] += uv.x * n0.x + uv.y * n0.y + uv.z * n0.z + uv.w * n0.w;
            acc1[bb] += uv.x * n1.x + uv.y * n1.y + uv.z * n1.z + uv.w * n1.w;
        }
    }
    #pragma unroll
    for (int bb = 0; bb < 8; ++bb) {
        int bi  = bg * 8 + bb;
        int it0 = item0 + jg * 2;
        if (it0     < N_ITEM) out[(size_t)bi * N_ITEM + it0]     = acc0[bb] + out_bias[it0];
        if (it0 + 1 < N_ITEM) out[(size_t)bi * N_ITEM + it0 + 1] = acc1[bb] + out_bias[it0 + 1];
    }
}

extern "C" void kernel_launch(void* const* d_in, const int* in_sizes, int n_in,
                              void* d_out, int out_size, void* d_ws, size_t ws_size,
                              hipStream_t stream)
{
    const int*   e_src     = (const int*)d_in[0];          // edge_idx[0]
    const int*   e_dst     = e_src + NEDGE;                // edge_idx[1]
    const int*   e_type    = (const int*)d_in[1];
    const int*   seed_ids  = (const int*)d_in[2];
    const int*   seed_len  = (const int*)d_in[3];
    // d_in[4] = labels (unused by reference)
    const float* basis     = (const float*)d_in[5];
    const float* att       = (const float*)d_in[6];
    const float* root      = (const float*)d_in[7];
    const float* rgcn_bias = (const float*)d_in[8];
    const float* attn_a    = (const float*)d_in[9];
    const float* attn_b    = (const float*)d_in[10];
    const float* out_bias  = (const float*)d_in[11];
    float*       out       = (float*)d_out;

    // workspace layout: cursor | bucket | nodes | u   (~6.3 MB)
    int*   cursor = (int*)d_ws;
    int*   bucket = cursor + 6928;
    float* nodes  = (float*)(bucket + (size_t)N_ITEM * CAP);
    float* u      = nodes + (size_t)N_ITEM * DIM;

    hipMemsetAsync(cursor, 0, 6928 * sizeof(int), stream);

    fill_kernel<<<(NEDGE / 4 + 255) / 256, 256, 0, stream>>>(
        e_src, e_dst, e_type, cursor, bucket);
    aggregate_kernel<<<(N_ITEM + 3) / 4, 256, 0, stream>>>(
        cursor, bucket, basis, att, rgcn_bias ? root : root, rgcn_bias, nodes);
    pool_kernel<<<BATCH, 256, 0, stream>>>(
        nodes, seed_ids, seed_len, attn_a, attn_b, u);
    score_kernel<<<(N_ITEM + ITEM_TILE - 1) / ITEM_TILE, 256, 0, stream>>>(
        nodes, u, out_bias, out);
}